// Round 13
// baseline (333.823 us; speedup 1.0000x reference)
//
#include <hip/hip_runtime.h>
#include <hip/hip_bf16.h>

// Fused attention block: B=4, N=2048, C=1024, H=16, D=64
//   q/k/v = x@W{q,k,v}; attn = softmax(qk^T/8); out = (attn@v)@Wo + bo
// Strategy: cast to bf16, MFMA GEMMs, flash attention on 32x32x16 MFMA:
// swapped QK^T (S^T), ONE in-lane softmax stream per wave (32 q-rows),
// P half-exchange via 2x __shfl_xor(32), SCALAR in-lane l (no ones-MFMA),
// merged both-tile trread issue + single drain + 8-MFMA PV cluster,
// ds_read_b64_tr_b16 PV (slot addressing), 2-phase dbuf K/V pipeline,
// XCD-chunked swizzle, defer-rescale (THR=8, log2 domain).

typedef __bf16 bf16x8 __attribute__((ext_vector_type(8)));   // 4 VGPRs, MFMA A/B frag
typedef __bf16 bf16x4 __attribute__((ext_vector_type(4)));   // 2 VGPRs, tr-read result
typedef float  f32x4  __attribute__((ext_vector_type(4)));   // 16x16 C/D frag
typedef float  f32x16 __attribute__((ext_vector_type(16)));  // 32x32 C/D frag
typedef unsigned int u32x4 __attribute__((ext_vector_type(4)));

#define LSCALE 0.18033688f   // (1/8) * log2(e): softmax in exp2 domain
#define DEFER_THR 8.0f       // skip rescale while max grows < 8 (log2): P <= 256

__device__ __forceinline__ f32x4 mfma16(bf16x8 a, bf16x8 b, f32x4 c) {
    return __builtin_amdgcn_mfma_f32_16x16x32_bf16(a, b, c, 0, 0, 0);
}

__device__ __forceinline__ f32x16 mfma32(bf16x8 a, bf16x8 b, f32x16 c) {
    return __builtin_amdgcn_mfma_f32_32x32x16_bf16(a, b, c, 0, 0, 0);
}

__device__ __forceinline__ unsigned short f2bf(float f) {
    unsigned u = __builtin_bit_cast(unsigned, f);
    u += 0x7fffu + ((u >> 16) & 1u);            // round-to-nearest-even
    return (unsigned short)(u >> 16);
}

__device__ __forceinline__ unsigned cvt_pk_bf16(float lo, float hi) {
    unsigned r;
    asm("v_cvt_pk_bf16_f32 %0, %1, %2" : "=v"(r) : "v"(lo), "v"(hi));
    return r;   // bits[15:0]=bf16(lo), bits[31:16]=bf16(hi)
}

// HW transpose read (slot semantics, verified R7): returns the 4 bf16 of
// column (addr&127)>>3 of the 4x16 row-major bf16 subtile at addr&~127.
__device__ __forceinline__ bf16x4 trread(unsigned addr) {
    bf16x4 d;
    asm volatile("ds_read_b64_tr_b16 %0, %1" : "=v"(d) : "v"(addr));
    return d;   // caller MUST s_waitcnt lgkmcnt + sched_barrier before use
}

__device__ __forceinline__ void gload16(const ushort* g, ushort* l) {
    __builtin_amdgcn_global_load_lds(
        (const __attribute__((address_space(1))) void*)g,
        (__attribute__((address_space(3))) void*)l, 16, 0, 0);
}

// ---------------- cast fp32 -> bf16 (vectorized) ----------------
__global__ void cast_bf16_kernel(const float4* __restrict__ in,
                                 ushort4* __restrict__ out, int n4) {
    int i = blockIdx.x * blockDim.x + threadIdx.x;
    if (i < n4) {
        float4 f = in[i];
        ushort4 r;
        r.x = f2bf(f.x); r.y = f2bf(f.y); r.z = f2bf(f.z); r.w = f2bf(f.w);
        out[i] = r;
    }
}

// ---------------- transpose + cast weights: Wt[n][k] = bf16(W[k][n]) --------
__global__ void transpose_cast_kernel(const float* __restrict__ Wq,
                                      const float* __restrict__ Wk,
                                      const float* __restrict__ Wv,
                                      const float* __restrict__ Wo,
                                      ushort* __restrict__ out) {
    __shared__ float tile[32][33];
    const int z = blockIdx.z;
    const float* W = (z == 0) ? Wq : (z == 1) ? Wk : (z == 2) ? Wv : Wo;
    ushort* o = out + (size_t)z * 1024 * 1024;
    const int k0 = blockIdx.x * 32, n0 = blockIdx.y * 32;
    const int tx = threadIdx.x, ty = threadIdx.y;   // (32,8)
#pragma unroll
    for (int i = 0; i < 4; i++)
        tile[ty + 8 * i][tx] = W[(size_t)(k0 + ty + 8 * i) * 1024 + n0 + tx];
    __syncthreads();
#pragma unroll
    for (int i = 0; i < 4; i++)
        o[(size_t)(n0 + ty + 8 * i) * 1024 + k0 + tx] = f2bf(tile[tx][ty + 8 * i]);
}

// ---------------- 128x128 MFMA GEMM, K=1024, BK=32 (m97-style) ----------------
// MODE 0, z==0 (Q): output pre-scaled by LSCALE (folds softmax scale into Q).
template <int MODE>
__global__ __launch_bounds__(256) void gemm128(const ushort* __restrict__ A,
                                               const ushort* __restrict__ Bt,
                                               ushort* __restrict__ outB,
                                               float* __restrict__ outF,
                                               const float* __restrict__ bias) {
    __shared__ ushort As[128 * 32];
    __shared__ ushort Bs[128 * 32];
    const int tid = threadIdx.x;
    const int lane = tid & 63;
    const int wid = tid >> 6;
    const int wm = wid >> 1, wn = wid & 1;
    const int m0 = blockIdx.x * 128;
    const int n0 = blockIdx.y * 128;
    if (MODE == 0) Bt += (size_t)blockIdx.z * (1024 * 1024);

    f32x4 acc[4][4] = {};

    for (int k0 = 0; k0 < 1024; k0 += 32) {
#pragma unroll
        for (int it = 0; it < 2; ++it) {
            int e = (it * 256 + tid) * 8;
            int r = e >> 5, c = e & 31;
            gload16(&A[(size_t)(m0 + r) * 1024 + k0 + c], &As[e]);
            gload16(&Bt[(size_t)(n0 + r) * 1024 + k0 + c], &Bs[e]);
        }
        __syncthreads();

        bf16x8 a[4], b[4];
#pragma unroll
        for (int i = 0; i < 4; i++) {
            a[i] = *(const bf16x8*)&As[(wm * 64 + i * 16 + (lane & 15)) * 32 + (lane >> 4) * 8];
            b[i] = *(const bf16x8*)&Bs[(wn * 64 + i * 16 + (lane & 15)) * 32 + (lane >> 4) * 8];
        }
#pragma unroll
        for (int i = 0; i < 4; i++)
#pragma unroll
            for (int j = 0; j < 4; j++)
                acc[i][j] = mfma16(a[i], b[j], acc[i][j]);
        __syncthreads();
    }

    const float scl = (MODE == 0 && blockIdx.z == 0) ? LSCALE : 1.0f;
#pragma unroll
    for (int i = 0; i < 4; i++) {
        int row_b = m0 + wm * 64 + i * 16 + ((lane >> 4) * 4);
#pragma unroll
        for (int j = 0; j < 4; j++) {
            int col = n0 + wn * 64 + j * 16 + (lane & 15);
#pragma unroll
            for (int r = 0; r < 4; r++) {
                int row = row_b + r;
                float v = acc[i][j][r] * scl;
                if (MODE == 0) {
                    ushort* o = outB + (size_t)blockIdx.z * (8192ull * 1024);
                    int b = row >> 11, n = row & 2047, h = col >> 6, d = col & 63;
                    o[((((size_t)(b * 16 + h)) * 2048 + n) << 6) + d] = f2bf(v);
                } else {
                    outF[(size_t)row * 1024 + col] = v + bias[col];
                }
            }
        }
    }
}

// ---------------- flash attention (32x32 MFMA) ----------------
// grid 1024 (XCD-chunk swizzled -> (qt, bh)). block 256 = 4 waves.
// Block owns 128 q-rows; wave owns 32 via one 32-col S^T tile.
// Q,K,V in [B,H,N,D] bf16 (Q pre-scaled). O -> bf16 [B,N,H*D].
__global__ __launch_bounds__(256, 4) void attn_kernel(const ushort* __restrict__ Q,
                                                      const ushort* __restrict__ K,
                                                      const ushort* __restrict__ V,
                                                      ushort* __restrict__ O) {
    __shared__ ushort Ks[2][64 * 64];     // dbuf, [key][d] XOR-swizzled (16KB)
    __shared__ ushort Vs[2][64 * 64];     // dbuf, 4 panels [64 key][16 d] (16KB)
    const int tid = threadIdx.x;
    const int lane = tid & 63;
    const int wid = tid >> 6;
    const int hi = lane >> 5;         // wave half
    const int q32 = lane & 31;        // this lane's q row (S^T col)
    const int bid = blockIdx.x;
    const int swz = (bid & 7) * 128 + (bid >> 3);   // XCD-chunked (1024 % 8 == 0)
    const int bh = swz >> 4;
    const int qt = swz & 15;
    const size_t base = (size_t)bh * (2048 * 64);

    // Q fragments: 32x32x16 B-operand (col=q32, k=8*hi+j), 4 d-chunks of 16
    const int qr = qt * 128 + wid * 32 + q32;
    bf16x8 qf[4];
#pragma unroll
    for (int dc = 0; dc < 4; ++dc)
        qf[dc] = *(const bf16x8*)&Q[base + (size_t)qr * 64 + dc * 16 + hi * 8];

    f32x16 o0 = {}, o1 = {};
    float l_run = 0.f;                // in-lane partial row-sum (this lane's 32 keys)
    float m_run = -1e30f;

    // per-thread staging chunk coordinates (constant across tiles)
    const int kci0 = tid, kci1 = 256 + tid;                 // K chunks
    const int kkey0 = kci0 >> 3, kd0 = (kci0 & 7) * 8;
    const int kkey1 = kci1 >> 3, kd1 = (kci1 & 7) * 8;
    const int kbyt0 = (kkey0 * 128 + kd0 * 2) ^ ((kkey0 & 7) << 4);
    const int kbyt1 = (kkey1 * 128 + kd1 * 2) ^ ((kkey1 & 7) << 4);
    const int vkey0 = (kci0 & 127) >> 1, vd0 = (kci0 >> 7) * 16 + (kci0 & 1) * 8;
    const int vkey1 = (kci1 & 127) >> 1, vd1 = (kci1 >> 7) * 16 + (kci1 & 1) * 8;

    char* const KsB0 = (char*)&Ks[0][0];
    ushort* const Vs0 = &Vs[0][0];
    const unsigned vb0 = (unsigned)(size_t)&Vs[0][0];

    // ---- prologue: stage tile 0 into buffer 0 ----
    {
        uint4 k0 = *(const uint4*)&K[base + (size_t)kkey0 * 64 + kd0];
        uint4 k1 = *(const uint4*)&K[base + (size_t)kkey1 * 64 + kd1];
        gload16(&V[base + (size_t)vkey0 * 64 + vd0], &Vs0[kci0 * 8]);
        gload16(&V[base + (size_t)vkey1 * 64 + vd1], &Vs0[kci1 * 8]);
        *(uint4*)(KsB0 + kbyt0) = k0;
        *(uint4*)(KsB0 + kbyt1) = k1;
    }
    __syncthreads();   // drains vmcnt(0)+lgkmcnt(0): tile 0 resident

    int cur = 0;
    for (int kt = 0; kt < 2048; kt += 64) {
        const int nxt = cur ^ 1;
        const bool more = (kt + 64) < 2048;
        char* const KsBc = KsB0 + cur * 8192;        // ptr math, not runtime idx
        const unsigned vbc = vb0 + cur * 8192;

        // ---- issue next tile's staging EARLY (hides HBM under compute) ----
        uint4 kn0, kn1;
        if (more) {
            const size_t nb = base + (size_t)(kt + 64) * 64;
            gload16(&V[nb + (size_t)vkey0 * 64 + vd0], &Vs0[nxt * 4096 + kci0 * 8]);
            gload16(&V[nb + (size_t)vkey1 * 64 + vd1], &Vs0[nxt * 4096 + kci1 * 8]);
            kn0 = *(const uint4*)&K[nb + (size_t)kkey0 * 64 + kd0];
            kn1 = *(const uint4*)&K[nb + (size_t)kkey1 * 64 + kd1];
        }

        // ---- S^T = K Q^T (two 32-key tiles):
        //      A=K(row=key=q32[+32], k=d), B=Q(col=q32, k=d)
        //      C: col=q32(q), row=key=(reg&3)+8*(reg>>2)+4*hi ----
        f32x16 s0 = {}, s1 = {};
        __builtin_amdgcn_s_setprio(1);
#pragma unroll
        for (int dc = 0; dc < 4; ++dc) {
            const int dby = (dc * 16 + hi * 8) * 2;
            bf16x8 kf0 = *(const bf16x8*)(KsBc + ((q32 * 128 + dby) ^ ((q32 & 7) << 4)));
            bf16x8 kf1 = *(const bf16x8*)(KsBc + (((32 + q32) * 128 + dby) ^ ((q32 & 7) << 4)));
            s0 = mfma32(kf0, qf[dc], s0);
            s1 = mfma32(kf1, qf[dc], s1);
        }
        __builtin_amdgcn_s_setprio(0);

        // ---- in-lane max over this lane's 32 keys + half-swap combine ----
        float ma = fmaxf(fmaxf(s0[0], s0[1]), fmaxf(s0[2], s0[3]));
        float mb = fmaxf(fmaxf(s0[4], s0[5]), fmaxf(s0[6], s0[7]));
        float mc = fmaxf(fmaxf(s0[8], s0[9]), fmaxf(s0[10], s0[11]));
        float md = fmaxf(fmaxf(s0[12], s0[13]), fmaxf(s0[14], s0[15]));
        float me = fmaxf(fmaxf(s1[0], s1[1]), fmaxf(s1[2], s1[3]));
        float mf = fmaxf(fmaxf(s1[4], s1[5]), fmaxf(s1[6], s1[7]));
        float mg = fmaxf(fmaxf(s1[8], s1[9]), fmaxf(s1[10], s1[11]));
        float mh = fmaxf(fmaxf(s1[12], s1[13]), fmaxf(s1[14], s1[15]));
        float mx = fmaxf(fmaxf(fmaxf(ma, mb), fmaxf(mc, md)),
                         fmaxf(fmaxf(me, mf), fmaxf(mg, mh)));
        mx = fmaxf(mx, __shfl_xor(mx, 32));   // lane pair holds complementary keys

        // ---- T13 defer-rescale (wave-uniform branch) ----
        if (!__all(mx <= m_run + DEFER_THR)) {
            float mn2 = fmaxf(m_run, mx);
            float fr = __builtin_amdgcn_exp2f(m_run - mn2);
            m_run = mn2;
            l_run *= fr;
#pragma unroll
            for (int r = 0; r < 16; ++r) {
                float f = __shfl(fr, (r & 3) + 8 * (r >> 2) + 4 * hi);
                o0[r] *= f; o1[r] *= f;
            }
        }
        const float mn = m_run;

        // ---- merged PV pipeline: issue ALL 16 trreads, pack both tiles,
        //      exchange, ONE drain, 8-MFMA cluster ----
        bf16x4 vv[16];
#pragma unroll
        for (int t = 0; t < 2; ++t)
#pragma unroll
            for (int h2 = 0; h2 < 2; ++h2) {
                const int kb = t * 32 + h2 * 16 + hi * 8;
#pragma unroll
                for (int dt = 0; dt < 2; ++dt) {
                    const int d = dt * 32 + q32;
                    unsigned a = vbc + (d >> 4) * 2048 + kb * 32 + (d & 15) * 8;
                    vv[t * 8 + h2 * 4 + dt * 2 + 0] = trread(a);
                    vv[t * 8 + h2 * 4 + dt * 2 + 1] = trread(a + 128);
                }
            }

        // exp + pack both tiles while trreads are in flight; in-lane l-sum
        // reg r of tile t -> key t*32 + (r&3)+8*(r>>2)+4*hi
        unsigned wA[2][2][2], wB[2][2][2];
        float tsum = 0.f;
#pragma unroll
        for (int t = 0; t < 2; ++t) {
            const f32x16 sv = t ? s1 : s0;   // compile-time select (unrolled)
#pragma unroll
            for (int h2 = 0; h2 < 2; ++h2) {
                float p0 = __builtin_amdgcn_exp2f(sv[8 * h2 + 0] - mn);
                float p1 = __builtin_amdgcn_exp2f(sv[8 * h2 + 1] - mn);
                float p2 = __builtin_amdgcn_exp2f(sv[8 * h2 + 2] - mn);
                float p3 = __builtin_amdgcn_exp2f(sv[8 * h2 + 3] - mn);
                float p4 = __builtin_amdgcn_exp2f(sv[8 * h2 + 4] - mn);
                float p5 = __builtin_amdgcn_exp2f(sv[8 * h2 + 5] - mn);
                float p6 = __builtin_amdgcn_exp2f(sv[8 * h2 + 6] - mn);
                float p7 = __builtin_amdgcn_exp2f(sv[8 * h2 + 7] - mn);
                wA[t][h2][0] = cvt_pk_bf16(p0, p1);   // keys 16h2+4hi+{0,1}
                wA[t][h2][1] = cvt_pk_bf16(p2, p3);   // keys 16h2+4hi+{2,3}
                wB[t][h2][0] = cvt_pk_bf16(p4, p5);   // keys 16h2+8+4hi+{0,1}
                wB[t][h2][1] = cvt_pk_bf16(p6, p7);   // keys 16h2+8+4hi+{2,3}
                tsum += ((p0 + p1) + (p2 + p3)) + ((p4 + p5) + (p6 + p7));
            }
        }
        l_run += tsum;

        // exchange (select-before-shuffle): lane sends partner's 2 words
        bf16x8 pa[2][2];
#pragma unroll
        for (int t = 0; t < 2; ++t)
#pragma unroll
            for (int h2 = 0; h2 < 2; ++h2) {
                unsigned m0 = hi ? wA[t][h2][0] : wB[t][h2][0];
                unsigned m1 = hi ? wA[t][h2][1] : wB[t][h2][1];
                unsigned x0 = __shfl_xor(m0, 32);
                unsigned x1 = __shfl_xor(m1, 32);
                u32x4 pw;
                pw.x = hi ? x0 : wA[t][h2][0];   // keys 16h2+8hi+{0,1}
                pw.y = hi ? x1 : wA[t][h2][1];   // keys 16h2+8hi+{2,3}
                pw.z = hi ? wB[t][h2][0] : x0;   // keys 16h2+8hi+{4,5}
                pw.w = hi ? wB[t][h2][1] : x1;   // keys 16h2+8hi+{6,7}
                pa[t][h2] = __builtin_bit_cast(bf16x8, pw);
            }

        asm volatile("s_waitcnt lgkmcnt(0)" ::: "memory");
        __builtin_amdgcn_sched_barrier(0);

        __builtin_amdgcn_s_setprio(1);
#pragma unroll
        for (int t = 0; t < 2; ++t)
#pragma unroll
            for (int h2 = 0; h2 < 2; ++h2) {
                const int vbase = t * 8 + h2 * 4;
                bf16x8 vf0 = __builtin_shufflevector(vv[vbase + 0], vv[vbase + 1],
                                                     0, 1, 2, 3, 4, 5, 6, 7);
                bf16x8 vf1 = __builtin_shufflevector(vv[vbase + 2], vv[vbase + 3],
                                                     0, 1, 2, 3, 4, 5, 6, 7);
                o0 = mfma32(pa[t][h2], vf0, o0);
                o1 = mfma32(pa[t][h2], vf1, o1);
            }
        __builtin_amdgcn_s_setprio(0);

        // ---- write next tile's K regs into buf nxt, single barrier ----
        if (more) {
            char* const KsBn = KsB0 + nxt * 8192;
            *(uint4*)(KsBn + kbyt0) = kn0;
            *(uint4*)(KsBn + kbyt1) = kn1;
        }
        __syncthreads();   // drains vmcnt (V DMA) + lgkmcnt (K writes)
        cur = nxt;
    }

    // ---- epilogue: combine lane-pair l, O /= l, write bf16 [B,N,H*D] ----
    const int b = bh >> 4, h = bh & 15;
    float lfull = l_run + __shfl_xor(l_run, 32);
    float inv = 1.0f / lfull;   // lane L holds inv for query q32
#pragma unroll
    for (int r = 0; r < 16; ++r) {
        int crow = (r & 3) + 8 * (r >> 2) + 4 * hi;
        float invr = __shfl(inv, crow);       // query crow's normalizer
        int row = qt * 128 + wid * 32 + crow;
        size_t rb = (size_t)(b * 2048 + row) * 1024 + h * 64;
        O[rb + q32]      = f2bf(o0[r] * invr);
        O[rb + 32 + q32] = f2bf(o1[r] * invr);
    }
}

// ---------------- launch ----------------
extern "C" void kernel_launch(void* const* d_in, const int* in_sizes, int n_in,
                              void* d_out, int out_size, void* d_ws, size_t ws_size,
                              hipStream_t stream) {
    const float* x  = (const float*)d_in[0];
    const float* Wq = (const float*)d_in[1];
    const float* Wk = (const float*)d_in[2];
    const float* Wv = (const float*)d_in[3];
    const float* Wo = (const float*)d_in[4];
    const float* bo = (const float*)d_in[5];
    float* out = (float*)d_out;

    if (ws_size < (size_t)72 * 1024 * 1024) return;
    ushort* ws  = (ushort*)d_ws;
    ushort* xb  = ws;
    ushort* wt  = xb + (size_t)8 * 1024 * 1024;
    ushort* qkv = wt + (size_t)4 * 1024 * 1024;
    ushort* ao  = xb;   // reuse xb after QKV GEMM consumed it

    cast_bf16_kernel<<<8192, 256, 0, stream>>>((const float4*)x, (ushort4*)xb,
                                               2 * 1024 * 1024);
    transpose_cast_kernel<<<dim3(32, 32, 4), dim3(32, 8), 0, stream>>>(Wq, Wk, Wv, Wo, wt);
    gemm128<0><<<dim3(64, 8, 3), 256, 0, stream>>>(xb, wt, qkv, nullptr, nullptr);
    attn_kernel<<<1024, 256, 0, stream>>>(
        qkv, qkv + (size_t)8 * 1024 * 1024, qkv + (size_t)16 * 1024 * 1024, ao);
    gemm128<1><<<dim3(64, 8, 1), 256, 0, stream>>>(ao, wt + (size_t)3 * 1024 * 1024,
                                                   nullptr, out, bo);
}

// Round 14
// 213.965 us; speedup vs baseline: 1.5602x; 1.5602x over previous
//
#include <hip/hip_runtime.h>
#include <hip/hip_bf16.h>

// Fused attention block: B=4, N=2048, C=1024, H=16, D=64
//   q/k/v = x@W{q,k,v}; attn = softmax(qk^T/8); out = (attn@v)@Wo + bo
// Strategy: cast to bf16, MFMA GEMMs, flash attention on 32x32x16 MFMA:
// swapped QK^T (S^T), ONE in-lane softmax stream per wave (32 q-rows),
// P half-exchange via 2x __shfl_xor(32), SCALAR in-lane l (no ones-MFMA),
// per-tile trread groups (vv[8] live; R13's merged vv[16]+launch-bounds
// clamp caused catastrophic spills), ds_read_b64_tr_b16 PV (slot addr),
// 2-phase dbuf K/V pipeline, XCD swizzle, defer-rescale (THR=8).

typedef __bf16 bf16x8 __attribute__((ext_vector_type(8)));   // 4 VGPRs, MFMA A/B frag
typedef __bf16 bf16x4 __attribute__((ext_vector_type(4)));   // 2 VGPRs, tr-read result
typedef float  f32x4  __attribute__((ext_vector_type(4)));   // 16x16 C/D frag
typedef float  f32x16 __attribute__((ext_vector_type(16)));  // 32x32 C/D frag
typedef unsigned int u32x4 __attribute__((ext_vector_type(4)));

#define LSCALE 0.18033688f   // (1/8) * log2(e): softmax in exp2 domain
#define DEFER_THR 8.0f       // skip rescale while max grows < 8 (log2): P <= 256

__device__ __forceinline__ f32x4 mfma16(bf16x8 a, bf16x8 b, f32x4 c) {
    return __builtin_amdgcn_mfma_f32_16x16x32_bf16(a, b, c, 0, 0, 0);
}

__device__ __forceinline__ f32x16 mfma32(bf16x8 a, bf16x8 b, f32x16 c) {
    return __builtin_amdgcn_mfma_f32_32x32x16_bf16(a, b, c, 0, 0, 0);
}

__device__ __forceinline__ unsigned short f2bf(float f) {
    unsigned u = __builtin_bit_cast(unsigned, f);
    u += 0x7fffu + ((u >> 16) & 1u);            // round-to-nearest-even
    return (unsigned short)(u >> 16);
}

__device__ __forceinline__ unsigned cvt_pk_bf16(float lo, float hi) {
    unsigned r;
    asm("v_cvt_pk_bf16_f32 %0, %1, %2" : "=v"(r) : "v"(lo), "v"(hi));
    return r;   // bits[15:0]=bf16(lo), bits[31:16]=bf16(hi)
}

// HW transpose read (slot semantics, verified R7): returns the 4 bf16 of
// column (addr&127)>>3 of the 4x16 row-major bf16 subtile at addr&~127.
__device__ __forceinline__ bf16x4 trread(unsigned addr) {
    bf16x4 d;
    asm volatile("ds_read_b64_tr_b16 %0, %1" : "=v"(d) : "v"(addr));
    return d;   // caller MUST s_waitcnt lgkmcnt + sched_barrier before use
}

__device__ __forceinline__ void gload16(const ushort* g, ushort* l) {
    __builtin_amdgcn_global_load_lds(
        (const __attribute__((address_space(1))) void*)g,
        (__attribute__((address_space(3))) void*)l, 16, 0, 0);
}

// ---------------- cast fp32 -> bf16 (vectorized) ----------------
__global__ void cast_bf16_kernel(const float4* __restrict__ in,
                                 ushort4* __restrict__ out, int n4) {
    int i = blockIdx.x * blockDim.x + threadIdx.x;
    if (i < n4) {
        float4 f = in[i];
        ushort4 r;
        r.x = f2bf(f.x); r.y = f2bf(f.y); r.z = f2bf(f.z); r.w = f2bf(f.w);
        out[i] = r;
    }
}

// ---------------- transpose + cast weights: Wt[n][k] = bf16(W[k][n]) --------
__global__ void transpose_cast_kernel(const float* __restrict__ Wq,
                                      const float* __restrict__ Wk,
                                      const float* __restrict__ Wv,
                                      const float* __restrict__ Wo,
                                      ushort* __restrict__ out) {
    __shared__ float tile[32][33];
    const int z = blockIdx.z;
    const float* W = (z == 0) ? Wq : (z == 1) ? Wk : (z == 2) ? Wv : Wo;
    ushort* o = out + (size_t)z * 1024 * 1024;
    const int k0 = blockIdx.x * 32, n0 = blockIdx.y * 32;
    const int tx = threadIdx.x, ty = threadIdx.y;   // (32,8)
#pragma unroll
    for (int i = 0; i < 4; i++)
        tile[ty + 8 * i][tx] = W[(size_t)(k0 + ty + 8 * i) * 1024 + n0 + tx];
    __syncthreads();
#pragma unroll
    for (int i = 0; i < 4; i++)
        o[(size_t)(n0 + ty + 8 * i) * 1024 + k0 + tx] = f2bf(tile[tx][ty + 8 * i]);
}

// ---------------- 128x128 MFMA GEMM, K=1024, BK=32 (m97-style) ----------------
// MODE 0, z==0 (Q): output pre-scaled by LSCALE (folds softmax scale into Q).
template <int MODE>
__global__ __launch_bounds__(256) void gemm128(const ushort* __restrict__ A,
                                               const ushort* __restrict__ Bt,
                                               ushort* __restrict__ outB,
                                               float* __restrict__ outF,
                                               const float* __restrict__ bias) {
    __shared__ ushort As[128 * 32];
    __shared__ ushort Bs[128 * 32];
    const int tid = threadIdx.x;
    const int lane = tid & 63;
    const int wid = tid >> 6;
    const int wm = wid >> 1, wn = wid & 1;
    const int m0 = blockIdx.x * 128;
    const int n0 = blockIdx.y * 128;
    if (MODE == 0) Bt += (size_t)blockIdx.z * (1024 * 1024);

    f32x4 acc[4][4] = {};

    for (int k0 = 0; k0 < 1024; k0 += 32) {
#pragma unroll
        for (int it = 0; it < 2; ++it) {
            int e = (it * 256 + tid) * 8;
            int r = e >> 5, c = e & 31;
            gload16(&A[(size_t)(m0 + r) * 1024 + k0 + c], &As[e]);
            gload16(&Bt[(size_t)(n0 + r) * 1024 + k0 + c], &Bs[e]);
        }
        __syncthreads();

        bf16x8 a[4], b[4];
#pragma unroll
        for (int i = 0; i < 4; i++) {
            a[i] = *(const bf16x8*)&As[(wm * 64 + i * 16 + (lane & 15)) * 32 + (lane >> 4) * 8];
            b[i] = *(const bf16x8*)&Bs[(wn * 64 + i * 16 + (lane & 15)) * 32 + (lane >> 4) * 8];
        }
#pragma unroll
        for (int i = 0; i < 4; i++)
#pragma unroll
            for (int j = 0; j < 4; j++)
                acc[i][j] = mfma16(a[i], b[j], acc[i][j]);
        __syncthreads();
    }

    const float scl = (MODE == 0 && blockIdx.z == 0) ? LSCALE : 1.0f;
#pragma unroll
    for (int i = 0; i < 4; i++) {
        int row_b = m0 + wm * 64 + i * 16 + ((lane >> 4) * 4);
#pragma unroll
        for (int j = 0; j < 4; j++) {
            int col = n0 + wn * 64 + j * 16 + (lane & 15);
#pragma unroll
            for (int r = 0; r < 4; r++) {
                int row = row_b + r;
                float v = acc[i][j][r] * scl;
                if (MODE == 0) {
                    ushort* o = outB + (size_t)blockIdx.z * (8192ull * 1024);
                    int b = row >> 11, n = row & 2047, h = col >> 6, d = col & 63;
                    o[((((size_t)(b * 16 + h)) * 2048 + n) << 6) + d] = f2bf(v);
                } else {
                    outF[(size_t)row * 1024 + col] = v + bias[col];
                }
            }
        }
    }
}

// ---------------- flash attention (32x32 MFMA) ----------------
// grid 1024 (XCD-chunk swizzled -> (qt, bh)). block 256 = 4 waves.
// Block owns 128 q-rows; wave owns 32 via one 32-col S^T tile.
// Q,K,V in [B,H,N,D] bf16 (Q pre-scaled). O -> bf16 [B,N,H*D].
__global__ __launch_bounds__(256) void attn_kernel(const ushort* __restrict__ Q,
                                                   const ushort* __restrict__ K,
                                                   const ushort* __restrict__ V,
                                                   ushort* __restrict__ O) {
    __shared__ ushort Ks[2][64 * 64];     // dbuf, [key][d] XOR-swizzled (16KB)
    __shared__ ushort Vs[2][64 * 64];     // dbuf, 4 panels [64 key][16 d] (16KB)
    const int tid = threadIdx.x;
    const int lane = tid & 63;
    const int wid = tid >> 6;
    const int hi = lane >> 5;         // wave half
    const int q32 = lane & 31;        // this lane's q row (S^T col)
    const int bid = blockIdx.x;
    const int swz = (bid & 7) * 128 + (bid >> 3);   // XCD-chunked (1024 % 8 == 0)
    const int bh = swz >> 4;
    const int qt = swz & 15;
    const size_t base = (size_t)bh * (2048 * 64);

    // Q fragments: 32x32x16 B-operand (col=q32, k=8*hi+j), 4 d-chunks of 16
    const int qr = qt * 128 + wid * 32 + q32;
    bf16x8 qf[4];
#pragma unroll
    for (int dc = 0; dc < 4; ++dc)
        qf[dc] = *(const bf16x8*)&Q[base + (size_t)qr * 64 + dc * 16 + hi * 8];

    f32x16 o0 = {}, o1 = {};
    float l_run = 0.f;                // in-lane partial row-sum (this lane's 32 keys)
    float m_run = -1e30f;

    // per-thread staging chunk coordinates (constant across tiles)
    const int kci0 = tid, kci1 = 256 + tid;                 // K chunks
    const int kkey0 = kci0 >> 3, kd0 = (kci0 & 7) * 8;
    const int kkey1 = kci1 >> 3, kd1 = (kci1 & 7) * 8;
    const int kbyt0 = (kkey0 * 128 + kd0 * 2) ^ ((kkey0 & 7) << 4);
    const int kbyt1 = (kkey1 * 128 + kd1 * 2) ^ ((kkey1 & 7) << 4);
    const int vkey0 = (kci0 & 127) >> 1, vd0 = (kci0 >> 7) * 16 + (kci0 & 1) * 8;
    const int vkey1 = (kci1 & 127) >> 1, vd1 = (kci1 >> 7) * 16 + (kci1 & 1) * 8;

    char* const KsB0 = (char*)&Ks[0][0];
    ushort* const Vs0 = &Vs[0][0];
    const unsigned vb0 = (unsigned)(size_t)&Vs[0][0];

    // ---- prologue: stage tile 0 into buffer 0 ----
    {
        uint4 k0 = *(const uint4*)&K[base + (size_t)kkey0 * 64 + kd0];
        uint4 k1 = *(const uint4*)&K[base + (size_t)kkey1 * 64 + kd1];
        gload16(&V[base + (size_t)vkey0 * 64 + vd0], &Vs0[kci0 * 8]);
        gload16(&V[base + (size_t)vkey1 * 64 + vd1], &Vs0[kci1 * 8]);
        *(uint4*)(KsB0 + kbyt0) = k0;
        *(uint4*)(KsB0 + kbyt1) = k1;
    }
    __syncthreads();   // drains vmcnt(0)+lgkmcnt(0): tile 0 resident

    int cur = 0;
    for (int kt = 0; kt < 2048; kt += 64) {
        const int nxt = cur ^ 1;
        const bool more = (kt + 64) < 2048;
        char* const KsBc = KsB0 + cur * 8192;        // ptr math, not runtime idx
        const unsigned vbc = vb0 + cur * 8192;

        // ---- issue next tile's staging EARLY (hides HBM under compute) ----
        uint4 kn0, kn1;
        if (more) {
            const size_t nb = base + (size_t)(kt + 64) * 64;
            gload16(&V[nb + (size_t)vkey0 * 64 + vd0], &Vs0[nxt * 4096 + kci0 * 8]);
            gload16(&V[nb + (size_t)vkey1 * 64 + vd1], &Vs0[nxt * 4096 + kci1 * 8]);
            kn0 = *(const uint4*)&K[nb + (size_t)kkey0 * 64 + kd0];
            kn1 = *(const uint4*)&K[nb + (size_t)kkey1 * 64 + kd1];
        }

        // ---- S^T = K Q^T (two 32-key tiles):
        //      A=K(row=key=q32[+32], k=d), B=Q(col=q32, k=d)
        //      C: col=q32(q), row=key=(reg&3)+8*(reg>>2)+4*hi ----
        f32x16 s0 = {}, s1 = {};
        __builtin_amdgcn_s_setprio(1);
#pragma unroll
        for (int dc = 0; dc < 4; ++dc) {
            const int dby = (dc * 16 + hi * 8) * 2;
            bf16x8 kf0 = *(const bf16x8*)(KsBc + ((q32 * 128 + dby) ^ ((q32 & 7) << 4)));
            bf16x8 kf1 = *(const bf16x8*)(KsBc + (((32 + q32) * 128 + dby) ^ ((q32 & 7) << 4)));
            s0 = mfma32(kf0, qf[dc], s0);
            s1 = mfma32(kf1, qf[dc], s1);
        }
        __builtin_amdgcn_s_setprio(0);

        // ---- in-lane max over this lane's 32 keys + half-swap combine ----
        float ma = fmaxf(fmaxf(s0[0], s0[1]), fmaxf(s0[2], s0[3]));
        float mb = fmaxf(fmaxf(s0[4], s0[5]), fmaxf(s0[6], s0[7]));
        float mc = fmaxf(fmaxf(s0[8], s0[9]), fmaxf(s0[10], s0[11]));
        float md = fmaxf(fmaxf(s0[12], s0[13]), fmaxf(s0[14], s0[15]));
        float me = fmaxf(fmaxf(s1[0], s1[1]), fmaxf(s1[2], s1[3]));
        float mf = fmaxf(fmaxf(s1[4], s1[5]), fmaxf(s1[6], s1[7]));
        float mg = fmaxf(fmaxf(s1[8], s1[9]), fmaxf(s1[10], s1[11]));
        float mh = fmaxf(fmaxf(s1[12], s1[13]), fmaxf(s1[14], s1[15]));
        float mx = fmaxf(fmaxf(fmaxf(ma, mb), fmaxf(mc, md)),
                         fmaxf(fmaxf(me, mf), fmaxf(mg, mh)));
        mx = fmaxf(mx, __shfl_xor(mx, 32));   // lane pair holds complementary keys

        // ---- T13 defer-rescale (wave-uniform branch) ----
        if (!__all(mx <= m_run + DEFER_THR)) {
            float mn2 = fmaxf(m_run, mx);
            float fr = __builtin_amdgcn_exp2f(m_run - mn2);
            m_run = mn2;
            l_run *= fr;
#pragma unroll
            for (int r = 0; r < 16; ++r) {
                float f = __shfl(fr, (r & 3) + 8 * (r >> 2) + 4 * hi);
                o0[r] *= f; o1[r] *= f;
            }
        }
        const float mn = m_run;

        // ---- per 32-key tile: V trreads -> exp+pack -> exchange -> MFMA ----
#pragma unroll
        for (int t = 0; t < 2; ++t) {
            const f32x16 sv = t ? s1 : s0;   // compile-time select (unrolled)

            // issue 8 trreads: chunks h2=0,1 (keys t*32+16*h2+8*hi+0..7), dt=0,1
            bf16x4 vv[8];
#pragma unroll
            for (int h2 = 0; h2 < 2; ++h2) {
                const int kb = t * 32 + h2 * 16 + hi * 8;
#pragma unroll
                for (int dt = 0; dt < 2; ++dt) {
                    const int d = dt * 32 + q32;
                    unsigned a = vbc + (d >> 4) * 2048 + kb * 32 + (d & 15) * 8;
                    vv[h2 * 4 + dt * 2 + 0] = trread(a);
                    vv[h2 * 4 + dt * 2 + 1] = trread(a + 128);
                }
            }

            // exp + pack while trreads are in flight; in-lane l partial sum
            // reg r -> key t*32 + (r&3)+8*(r>>2)+4*hi
            unsigned wA[2][2], wB[2][2];
            float tsum = 0.f;
#pragma unroll
            for (int h2 = 0; h2 < 2; ++h2) {
                float p0 = __builtin_amdgcn_exp2f(sv[8 * h2 + 0] - mn);
                float p1 = __builtin_amdgcn_exp2f(sv[8 * h2 + 1] - mn);
                float p2 = __builtin_amdgcn_exp2f(sv[8 * h2 + 2] - mn);
                float p3 = __builtin_amdgcn_exp2f(sv[8 * h2 + 3] - mn);
                float p4 = __builtin_amdgcn_exp2f(sv[8 * h2 + 4] - mn);
                float p5 = __builtin_amdgcn_exp2f(sv[8 * h2 + 5] - mn);
                float p6 = __builtin_amdgcn_exp2f(sv[8 * h2 + 6] - mn);
                float p7 = __builtin_amdgcn_exp2f(sv[8 * h2 + 7] - mn);
                wA[h2][0] = cvt_pk_bf16(p0, p1);   // keys 16h2+4hi+{0,1}
                wA[h2][1] = cvt_pk_bf16(p2, p3);   // keys 16h2+4hi+{2,3}
                wB[h2][0] = cvt_pk_bf16(p4, p5);   // keys 16h2+8+4hi+{0,1}
                wB[h2][1] = cvt_pk_bf16(p6, p7);   // keys 16h2+8+4hi+{2,3}
                tsum += ((p0 + p1) + (p2 + p3)) + ((p4 + p5) + (p6 + p7));
            }
            l_run += tsum;

            asm volatile("s_waitcnt lgkmcnt(0)" ::: "memory");
            __builtin_amdgcn_sched_barrier(0);

            __builtin_amdgcn_s_setprio(1);
#pragma unroll
            for (int h2 = 0; h2 < 2; ++h2) {
                // A-frag needs keys 16h2 + 8*hi + j. Select-before-shuffle:
                // each lane sends the 2 words its partner needs.
                unsigned m0 = hi ? wA[h2][0] : wB[h2][0];
                unsigned m1 = hi ? wA[h2][1] : wB[h2][1];
                unsigned x0 = __shfl_xor(m0, 32);   // lo gets hi's wA; hi gets lo's wB
                unsigned x1 = __shfl_xor(m1, 32);
                u32x4 pw;
                pw.x = hi ? x0 : wA[h2][0];   // keys 16h2+8hi+{0,1}
                pw.y = hi ? x1 : wA[h2][1];   // keys 16h2+8hi+{2,3}
                pw.z = hi ? wB[h2][0] : x0;   // keys 16h2+8hi+{4,5}
                pw.w = hi ? wB[h2][1] : x1;   // keys 16h2+8hi+{6,7}
                bf16x8 pa = __builtin_bit_cast(bf16x8, pw);

                bf16x8 vf0 = __builtin_shufflevector(vv[h2 * 4 + 0], vv[h2 * 4 + 1],
                                                     0, 1, 2, 3, 4, 5, 6, 7);
                bf16x8 vf1 = __builtin_shufflevector(vv[h2 * 4 + 2], vv[h2 * 4 + 3],
                                                     0, 1, 2, 3, 4, 5, 6, 7);
                o0 = mfma32(pa, vf0, o0);
                o1 = mfma32(pa, vf1, o1);
            }
            __builtin_amdgcn_s_setprio(0);
        }

        // ---- write next tile's K regs into buf nxt, single barrier ----
        if (more) {
            char* const KsBn = KsB0 + nxt * 8192;
            *(uint4*)(KsBn + kbyt0) = kn0;
            *(uint4*)(KsBn + kbyt1) = kn1;
        }
        __syncthreads();   // drains vmcnt (V DMA) + lgkmcnt (K writes)
        cur = nxt;
    }

    // ---- epilogue: combine lane-pair l, O /= l, write bf16 [B,N,H*D] ----
    const int b = bh >> 4, h = bh & 15;
    float lfull = l_run + __shfl_xor(l_run, 32);
    float inv = 1.0f / lfull;   // lane L holds inv for query q32
#pragma unroll
    for (int r = 0; r < 16; ++r) {
        int crow = (r & 3) + 8 * (r >> 2) + 4 * hi;
        float invr = __shfl(inv, crow);       // query crow's normalizer
        int row = qt * 128 + wid * 32 + crow;
        size_t rb = (size_t)(b * 2048 + row) * 1024 + h * 64;
        O[rb + q32]      = f2bf(o0[r] * invr);
        O[rb + 32 + q32] = f2bf(o1[r] * invr);
    }
}

// ---------------- launch ----------------
extern "C" void kernel_launch(void* const* d_in, const int* in_sizes, int n_in,
                              void* d_out, int out_size, void* d_ws, size_t ws_size,
                              hipStream_t stream) {
    const float* x  = (const float*)d_in[0];
    const float* Wq = (const float*)d_in[1];
    const float* Wk = (const float*)d_in[2];
    const float* Wv = (const float*)d_in[3];
    const float* Wo = (const float*)d_in[4];
    const float* bo = (const float*)d_in[5];
    float* out = (float*)d_out;

    if (ws_size < (size_t)72 * 1024 * 1024) return;
    ushort* ws  = (ushort*)d_ws;
    ushort* xb  = ws;
    ushort* wt  = xb + (size_t)8 * 1024 * 1024;
    ushort* qkv = wt + (size_t)4 * 1024 * 1024;
    ushort* ao  = xb;   // reuse xb after QKV GEMM consumed it

    cast_bf16_kernel<<<8192, 256, 0, stream>>>((const float4*)x, (ushort4*)xb,
                                               2 * 1024 * 1024);
    transpose_cast_kernel<<<dim3(32, 32, 4), dim3(32, 8), 0, stream>>>(Wq, Wk, Wv, Wo, wt);
    gemm128<0><<<dim3(64, 8, 3), 256, 0, stream>>>(xb, wt, qkv, nullptr, nullptr);
    attn_kernel<<<1024, 256, 0, stream>>>(
        qkv, qkv + (size_t)8 * 1024 * 1024, qkv + (size_t)16 * 1024 * 1024, ao);
    gemm128<1><<<dim3(64, 8, 1), 256, 0, stream>>>(ao, wt + (size_t)3 * 1024 * 1024,
                                                   nullptr, out, bo);
}